// Round 1
// baseline (228.810 us; speedup 1.0000x reference)
//
#include <hip/hip_runtime.h>

// Dense image warp (bilinear), B=8 H=256 W=256 C=64, fp32.
// One thread = one float4 (4 channels) of one output pixel.
// 16 threads per pixel; out float4 index == global thread id (coalesced).

__global__ __launch_bounds__(256) void warp_bilinear_kernel(
    const float* __restrict__ image,
    const float* __restrict__ flow,
    float* __restrict__ out)
{
    constexpr int H = 256, W = 256, C = 64;
    constexpr int QUADS = C / 4;  // 16 float4 per pixel

    const int gid = blockIdx.x * blockDim.x + threadIdx.x;
    const int p = gid >> 4;       // pixel index: b*H*W + y*W + x
    const int q = gid & 15;       // channel quad within pixel

    const int x = p & (W - 1);
    const int y = (p >> 8) & (H - 1);
    const int b = p >> 16;

    // query point = grid - flow
    const float qy = (float)y - flow[2 * p + 0];
    const float qx = (float)x - flow[2 * p + 1];

    // floor clamped to [0, size-2]; alpha clipped to [0,1] (tfa semantics)
    const float fy = fminf(fmaxf(floorf(qy), 0.0f), (float)(H - 2));
    const float fx = fminf(fmaxf(floorf(qx), 0.0f), (float)(W - 2));
    const float ay = fminf(fmaxf(qy - fy, 0.0f), 1.0f);
    const float ax = fminf(fmaxf(qx - fx, 0.0f), 1.0f);
    const int iy = (int)fy;
    const int ix = (int)fx;

    const float4* __restrict__ img4 = (const float4*)image;
    // float4-unit index of (b, iy, ix, 4q)
    const long base = (((long)(b * H + iy)) * W + ix) * QUADS + q;
    const long rowstep = (long)W * QUADS;

    const float4 tl = img4[base];
    const float4 tr = img4[base + QUADS];
    const float4 bl = img4[base + rowstep];
    const float4 br = img4[base + rowstep + QUADS];

    float4 r;
    {
        float top, bot;
        top = fmaf(ax, tr.x - tl.x, tl.x);
        bot = fmaf(ax, br.x - bl.x, bl.x);
        r.x = fmaf(ay, bot - top, top);
        top = fmaf(ax, tr.y - tl.y, tl.y);
        bot = fmaf(ax, br.y - bl.y, bl.y);
        r.y = fmaf(ay, bot - top, top);
        top = fmaf(ax, tr.z - tl.z, tl.z);
        bot = fmaf(ax, br.z - bl.z, bl.z);
        r.z = fmaf(ay, bot - top, top);
        top = fmaf(ax, tr.w - tl.w, tl.w);
        bot = fmaf(ax, br.w - bl.w, bl.w);
        r.w = fmaf(ay, bot - top, top);
    }

    ((float4*)out)[gid] = r;
}

extern "C" void kernel_launch(void* const* d_in, const int* in_sizes, int n_in,
                              void* d_out, int out_size, void* d_ws, size_t ws_size,
                              hipStream_t stream) {
    const float* image = (const float*)d_in[0];
    const float* flow  = (const float*)d_in[1];
    float* out = (float*)d_out;

    constexpr int B = 8, H = 256, W = 256, C = 64;
    const int total_threads = B * H * W * (C / 4);  // 8,388,608
    const int block = 256;
    const int grid = total_threads / block;         // 32,768

    warp_bilinear_kernel<<<grid, block, 0, stream>>>(image, flow, out);
}